// Round 6
// baseline (243.602 us; speedup 1.0000x reference)
//
#include <hip/hip_runtime.h>
#include <hip/hip_bf16.h>

typedef __attribute__((ext_vector_type(8))) short bf16x8;
typedef __attribute__((ext_vector_type(4))) float f32x4;

#define S_LEN 2048
#define EMB   1024
#define NH    16
#define HD    64

// XOR-swizzled LDS addressing: 64-col bf16 tiles, 8-elem (16 B) chunks.
// elem(row, chunk) = row*64 + ((chunk ^ (row&7))*8).
// Staging writes AND all fragment reads are bank-uniform (verified by
// construction: 8 lanes per 4-bank group covering all 32 banks -> 8-cyc
// optimum per b128). The round-5 pad-72 layout was 8-way conflicted on
// both writes and reads (stride 72 elems = 4 banks mod 32).
__device__ inline int swz(int row, int chunk) {
  return row * 64 + ((chunk ^ (row & 7)) << 3);
}

// K-row permutation: storing K row s at position [s5,s2,s4,s3,s1,s0] makes
// the exp(S^T) C-layout registers exactly the mfma_16x16x32 A-fragment for
// natural-order V (key at position p is [p5,p3,p2,p4,p1,p0]); PV then uses
// K=32 MFMA with b128 V reads and zero cross-lane fixup.
__device__ inline int kperm(int s) {
  return (s & 0x23) | ((s & 0x04) << 2) | ((s & 0x18) >> 1);
}

// Convert 8 contiguous f32 -> 8 bf16 (RNE) packed in a uint4, optional scale.
__device__ inline uint4 cvt8(const float* __restrict__ src, float scale) {
  float4 f0 = ((const float4*)src)[0];
  float4 f1 = ((const float4*)src)[1];
  __hip_bfloat16 t[8];
  t[0] = __float2bfloat16(f0.x * scale);
  t[1] = __float2bfloat16(f0.y * scale);
  t[2] = __float2bfloat16(f0.z * scale);
  t[3] = __float2bfloat16(f0.w * scale);
  t[4] = __float2bfloat16(f1.x * scale);
  t[5] = __float2bfloat16(f1.y * scale);
  t[6] = __float2bfloat16(f1.z * scale);
  t[7] = __float2bfloat16(f1.w * scale);
  return *(uint4*)t;
}

// ---------------------------------------------------------------------------
// prep: z<2 -> K/V reformat for batch b=z; z==2 -> W f32->bf16 convert.
//   Kb[((b*NH+h)*S + s)*64 + d]  (head-major, rows = keys)
//   Vt[((b*NH+h)*64 + d)*S + s]  (transposed, rows = dims)
// ---------------------------------------------------------------------------
__global__ __launch_bounds__(256)
void prep(const float* __restrict__ K, const float* __restrict__ V,
          const float* __restrict__ W,
          __hip_bfloat16* __restrict__ Kb, __hip_bfloat16* __restrict__ Vt,
          __hip_bfloat16* __restrict__ Wb) {
  const int tid = threadIdx.x;
  if (blockIdx.z == 2) {   // W convert: 512 virtual blocks x 2048 elems
    const int widx = blockIdx.y * 32 + blockIdx.x;
    const int i = (widx * 256 + tid) * 8;
    *(uint4*)(Wb + i) = cvt8(W + i, 1.0f);
    return;
  }
  __shared__ float vt[64 * 65];
  const int st = blockIdx.x, h = blockIdx.y, b = blockIdx.z;
  const size_t srcbase = ((size_t)(b * S_LEN + st * 64)) * EMB + h * HD;
  const size_t kvb = ((size_t)(b * NH + h) * S_LEN + st * 64) * HD;
  const size_t vtb = ((size_t)(b * NH + h) * HD) * S_LEN + st * 64;

  for (int c = tid; c < 512; c += 256) {
    const int r = c >> 3, c8 = (c & 7) * 8;
    *(uint4*)(Kb + kvb + r * HD + c8) = cvt8(K + srcbase + (size_t)r * EMB + c8, 1.0f);
    const float* vsrc = V + srcbase + (size_t)r * EMB + c8;
    float4 a = ((const float4*)vsrc)[0];
    float4 d4 = ((const float4*)vsrc)[1];
    float tv[8] = {a.x, a.y, a.z, a.w, d4.x, d4.y, d4.z, d4.w};
    #pragma unroll
    for (int j = 0; j < 8; ++j) vt[r * 65 + c8 + j] = tv[j];
  }
  __syncthreads();
  for (int c = tid; c < 512; c += 256) {
    const int d = c >> 3, s8 = (c & 7) * 8;
    __hip_bfloat16 t[8];
    #pragma unroll
    for (int j = 0; j < 8; ++j)
      t[j] = __float2bfloat16(vt[(s8 + j) * 65 + d]);
    *(uint4*)(Vt + vtb + (size_t)d * S_LEN + s8) = *(uint4*)t;
  }
}

// ---------------------------------------------------------------------------
// Flash attention v5: S^T = K Q^T; exp(S^T) feeds PV directly from registers.
// 256 threads = 4 waves x 32 queries (qn=0,1) -> 128 q/block, grid 512 =
// 2 blocks/CU (48 KB LDS each), 8 waves/CU. XOR-swizzled LDS (conflict-free),
// permuted K rows enable K=32 PV MFMAs with b128 V reads. Double-buffered
// K/V + register prefetch; one barrier per K-iteration.
// ---------------------------------------------------------------------------
__global__ __launch_bounds__(256, 2)
void attn_fwd(const float* __restrict__ Q,
              const __hip_bfloat16* __restrict__ Kb,
              const __hip_bfloat16* __restrict__ Vt,
              __hip_bfloat16* __restrict__ O)
{
  __shared__ __align__(16) __hip_bfloat16 qs[128 * 64];     // 16 KB
  __shared__ __align__(16) __hip_bfloat16 ks[2][64 * 64];   // 16 KB [key][dim]
  __shared__ __align__(16) __hip_bfloat16 vs[2][64 * 64];   // 16 KB [dim][key]

  const int qt   = blockIdx.x;
  const int h    = blockIdx.y;
  const int b    = blockIdx.z;
  const int tid  = threadIdx.x;
  const int wave = tid >> 6;
  const int lane = tid & 63;
  const int ln   = lane & 15;
  const int qd   = lane >> 4;

  const size_t baseQ = ((size_t)(b * S_LEN + qt * 128)) * EMB + h * HD;
  const size_t kvb   = ((size_t)(b * NH + h) * S_LEN) * HD;
  const size_t vtb   = ((size_t)(b * NH + h) * HD) * S_LEN;

  // staging: 512 chunks per tile, 256 threads -> 2 chunks each
  const int ra = tid >> 3, rb = ra + 32, cc = tid & 7;
  const int kpa = swz(kperm(ra), cc), kpb = swz(kperm(rb), cc);  // loop-invariant
  const int vpa = swz(ra, cc),        vpb = swz(rb, cc);

  // prefetch tile 0
  uint4 krg[2], vrg[2];
  krg[0] = *(const uint4*)(Kb + kvb + (size_t)ra * HD + cc * 8);
  krg[1] = *(const uint4*)(Kb + kvb + (size_t)rb * HD + cc * 8);
  vrg[0] = *(const uint4*)(Vt + vtb + (size_t)ra * S_LEN + cc * 8);
  vrg[1] = *(const uint4*)(Vt + vtb + (size_t)rb * S_LEN + cc * 8);

  // stage Q (f32 -> bf16, scale = 0.125*log2(e); P = exp2(S'))
  const float qscale = 0.125f * 1.44269504088896f;
  for (int i = 0; i < 4; ++i) {
    const int c = tid + 256 * i, row = c >> 3, ch = c & 7;
    *(uint4*)&qs[swz(row, ch)] = cvt8(Q + baseQ + (size_t)row * EMB + ch * 8, qscale);
  }
  // write tile 0, prefetch tile 1
  *(uint4*)&ks[0][kpa] = krg[0];  *(uint4*)&ks[0][kpb] = krg[1];
  *(uint4*)&vs[0][vpa] = vrg[0];  *(uint4*)&vs[0][vpb] = vrg[1];
  krg[0] = *(const uint4*)(Kb + kvb + (size_t)(64 + ra) * HD + cc * 8);
  krg[1] = *(const uint4*)(Kb + kvb + (size_t)(64 + rb) * HD + cc * 8);
  vrg[0] = *(const uint4*)(Vt + vtb + (size_t)ra * S_LEN + 64 + cc * 8);
  vrg[1] = *(const uint4*)(Vt + vtb + (size_t)rb * S_LEN + 64 + cc * 8);
  __syncthreads();   // qs + buf0 ready

  // Q B-fragments (n = query = ln, k = qd*8+j), loop-invariant
  bf16x8 aq[2][2];
  #pragma unroll
  for (int qn = 0; qn < 2; ++qn)
    #pragma unroll
    for (int kh = 0; kh < 2; ++kh)
      aq[qn][kh] = *(const bf16x8*)&qs[swz(wave * 32 + qn * 16 + ln, kh * 4 + qd)];

  f32x4 oacc[2][4] = {};   // [qn][dn]; C: col=dim=ln, row=query=qd*4+r
  float lsum[2] = {};

  for (int kt = 0; kt < S_LEN / 64; ++kt) {
    const int cur = kt & 1;
    if (kt + 1 < S_LEN / 64) {     // regs loaded one full iter ago: no stall
      *(uint4*)&ks[1 - cur][kpa] = krg[0];  *(uint4*)&ks[1 - cur][kpb] = krg[1];
      *(uint4*)&vs[1 - cur][vpa] = vrg[0];  *(uint4*)&vs[1 - cur][vpb] = vrg[1];
      if (kt + 2 < S_LEN / 64) {
        const size_t ko = kvb + (size_t)(kt + 2) * 64 * HD;
        krg[0] = *(const uint4*)(Kb + ko + (size_t)ra * HD + cc * 8);
        krg[1] = *(const uint4*)(Kb + ko + (size_t)rb * HD + cc * 8);
        const size_t vo = vtb + (size_t)(kt + 2) * 64;
        vrg[0] = *(const uint4*)(Vt + vo + (size_t)ra * S_LEN + cc * 8);
        vrg[1] = *(const uint4*)(Vt + vo + (size_t)rb * S_LEN + cc * 8);
      }
    }

    // ---- S^T = K Q^T (rows = permuted keys) ----
    f32x4 sf[2][4];
    #pragma unroll
    for (int kt16 = 0; kt16 < 4; ++kt16) {
      bf16x8 ak0 = *(const bf16x8*)&ks[cur][swz(kt16 * 16 + ln, qd)];
      bf16x8 ak1 = *(const bf16x8*)&ks[cur][swz(kt16 * 16 + ln, 4 + qd)];
      #pragma unroll
      for (int qn = 0; qn < 2; ++qn) {
        f32x4 acc = {};
        acc = __builtin_amdgcn_mfma_f32_16x16x32_bf16(ak0, aq[qn][0], acc, 0, 0, 0);
        acc = __builtin_amdgcn_mfma_f32_16x16x32_bf16(ak1, aq[qn][1], acc, 0, 0, 0);
        sf[qn][kt16] = acc;
      }
    }

    // ---- P = exp2(S'); pack straight into K=32 A-fragments ----
    // key at k-index qd*8+j lives at S^T tile kt16 = t*2+(j>>2), reg j&3
    bf16x8 ap[2][2];
    #pragma unroll
    for (int qn = 0; qn < 2; ++qn)
      #pragma unroll
      for (int t = 0; t < 2; ++t)
        #pragma unroll
        for (int j = 0; j < 8; ++j) {
          const float p = exp2f(sf[qn][t * 2 + (j >> 2)][j & 3]);
          lsum[qn] += p;
          __hip_bfloat16 hb = __float2bfloat16(p);
          ap[qn][t][j] = *(short*)&hb;
        }

    // ---- O += P V : K=32 MFMA, V b128 reads from vs[dim][key] ----
    #pragma unroll
    for (int t = 0; t < 2; ++t)
      #pragma unroll
      for (int dn = 0; dn < 4; ++dn) {
        bf16x8 bv = *(const bf16x8*)&vs[cur][swz(dn * 16 + ln, t * 4 + qd)];
        #pragma unroll
        for (int qn = 0; qn < 2; ++qn)
          oacc[qn][dn] = __builtin_amdgcn_mfma_f32_16x16x32_bf16(
              ap[qn][t], bv, oacc[qn][dn], 0, 0, 0);
      }

    __syncthreads();   // single barrier per iteration
  }

  // ---- epilogue: reduce lsum across quads, redistribute, normalize ----
  #pragma unroll
  for (int qn = 0; qn < 2; ++qn) {
    lsum[qn] += __shfl_xor(lsum[qn], 16);
    lsum[qn] += __shfl_xor(lsum[qn], 32);
  }
  #pragma unroll
  for (int qn = 0; qn < 2; ++qn)
    #pragma unroll
    for (int r = 0; r < 4; ++r) {
      const float inv = 1.f / __shfl(lsum[qn], qd * 4 + r);
      const int row = wave * 32 + qn * 16 + qd * 4 + r;
      #pragma unroll
      for (int dn = 0; dn < 4; ++dn)
        O[baseQ + (size_t)row * EMB + dn * 16 + ln] =
            __float2bfloat16(oacc[qn][dn][r] * inv);
    }
}

// ---------------------------------------------------------------------------
// Projection: Out = PReLU(X @ W^T + b). 128x128 tile, 512 thr = 8 waves in a
// 4(M) x 2(N) grid (32 rows x 64 cols each). XOR-swizzled LDS, double-
// buffered, one barrier per k-iteration.
// ---------------------------------------------------------------------------
__global__ __launch_bounds__(512, 2)
void proj_prelu(const __hip_bfloat16* __restrict__ X,
                const __hip_bfloat16* __restrict__ Wb,
                const float* __restrict__ Bv,
                const float* __restrict__ Pa,
                float* __restrict__ Out)
{
  __shared__ __align__(16) __hip_bfloat16 xs[2][128 * 64];   // 32 KB
  __shared__ __align__(16) __hip_bfloat16 wsm[2][128 * 64];  // 32 KB

  const int m0   = blockIdx.x * 128;
  const int n0   = blockIdx.y * 128;
  const int tid  = threadIdx.x;
  const int wave = tid >> 6;
  const int wm   = wave >> 1;      // 0..3 : 32-row strip
  const int wn   = wave & 1;       // 0..1 : 64-col strip
  const int lane = tid & 63;
  const int ln   = lane & 15;
  const int qd   = lane >> 4;

  // staging: 1024 chunks per array / 512 thr = 2 each
  const int ra = tid >> 3, rb = ra + 64, cc = tid & 7;
  const int pa = swz(ra, cc), pb = swz(rb, cc);

  f32x4 acc[2][4] = {};   // [mf][nf]

  uint4 xrg[2], wrg[2];
  xrg[0] = *(const uint4*)(X  + (size_t)(m0 + ra) * EMB + cc * 8);
  xrg[1] = *(const uint4*)(X  + (size_t)(m0 + rb) * EMB + cc * 8);
  wrg[0] = *(const uint4*)(Wb + (size_t)(n0 + ra) * EMB + cc * 8);
  wrg[1] = *(const uint4*)(Wb + (size_t)(n0 + rb) * EMB + cc * 8);
  *(uint4*)&xs[0][pa]  = xrg[0];  *(uint4*)&xs[0][pb]  = xrg[1];
  *(uint4*)&wsm[0][pa] = wrg[0];  *(uint4*)&wsm[0][pb] = wrg[1];
  xrg[0] = *(const uint4*)(X  + (size_t)(m0 + ra) * EMB + 64 + cc * 8);
  xrg[1] = *(const uint4*)(X  + (size_t)(m0 + rb) * EMB + 64 + cc * 8);
  wrg[0] = *(const uint4*)(Wb + (size_t)(n0 + ra) * EMB + 64 + cc * 8);
  wrg[1] = *(const uint4*)(Wb + (size_t)(n0 + rb) * EMB + 64 + cc * 8);
  __syncthreads();

  for (int kt = 0; kt < EMB / 64; ++kt) {
    const int cur = kt & 1;
    if (kt + 1 < EMB / 64) {
      *(uint4*)&xs[1 - cur][pa]  = xrg[0];  *(uint4*)&xs[1 - cur][pb]  = xrg[1];
      *(uint4*)&wsm[1 - cur][pa] = wrg[0];  *(uint4*)&wsm[1 - cur][pb] = wrg[1];
      if (kt + 2 < EMB / 64) {
        const int ko = (kt + 2) * 64;
        xrg[0] = *(const uint4*)(X  + (size_t)(m0 + ra) * EMB + ko + cc * 8);
        xrg[1] = *(const uint4*)(X  + (size_t)(m0 + rb) * EMB + ko + cc * 8);
        wrg[0] = *(const uint4*)(Wb + (size_t)(n0 + ra) * EMB + ko + cc * 8);
        wrg[1] = *(const uint4*)(Wb + (size_t)(n0 + rb) * EMB + ko + cc * 8);
      }
    }

    #pragma unroll
    for (int kh = 0; kh < 2; ++kh) {
      bf16x8 ax[2], bw[4];
      #pragma unroll
      for (int mf = 0; mf < 2; ++mf)
        ax[mf] = *(const bf16x8*)&xs[cur][swz(wm * 32 + mf * 16 + ln, kh * 4 + qd)];
      #pragma unroll
      for (int nf = 0; nf < 4; ++nf)
        bw[nf] = *(const bf16x8*)&wsm[cur][swz(wn * 64 + nf * 16 + ln, kh * 4 + qd)];
      #pragma unroll
      for (int mf = 0; mf < 2; ++mf)
        #pragma unroll
        for (int nf = 0; nf < 4; ++nf)
          acc[mf][nf] = __builtin_amdgcn_mfma_f32_16x16x32_bf16(
              ax[mf], bw[nf], acc[mf][nf], 0, 0, 0);
    }
    __syncthreads();
  }

  const float a = Pa[0];
  #pragma unroll
  for (int nf = 0; nf < 4; ++nf) {
    const float bn = Bv[n0 + wn * 64 + nf * 16 + ln];
    #pragma unroll
    for (int mf = 0; mf < 2; ++mf)
      #pragma unroll
      for (int r = 0; r < 4; ++r) {
        float y = acc[mf][nf][r] + bn;
        y = (y >= 0.f) ? y : a * y;
        Out[(size_t)(m0 + wm * 32 + mf * 16 + qd * 4 + r) * EMB +
            n0 + wn * 64 + nf * 16 + ln] = y;
      }
  }
}

extern "C" void kernel_launch(void* const* d_in, const int* in_sizes, int n_in,
                              void* d_out, int out_size, void* d_ws, size_t ws_size,
                              hipStream_t stream) {
  const float* Q  = (const float*)d_in[0];
  const float* K  = (const float*)d_in[1];
  const float* V  = (const float*)d_in[2];
  const float* W  = (const float*)d_in[3];
  const float* Bb = (const float*)d_in[4];
  const float* Pa = (const float*)d_in[5];
  float* Out = (float*)d_out;

  // workspace (bytes): X 0..8M, Kb 8M..16M, Vt 16M..24M, Wb 24M..26M
  char* ws = (char*)d_ws;
  __hip_bfloat16* Xws = (__hip_bfloat16*)(ws);
  __hip_bfloat16* Kb  = (__hip_bfloat16*)(ws + (8u  << 20));
  __hip_bfloat16* Vt  = (__hip_bfloat16*)(ws + (16u << 20));
  __hip_bfloat16* Wb  = (__hip_bfloat16*)(ws + (24u << 20));

  prep      <<<dim3(S_LEN / 64, NH, 3), 256, 0, stream>>>(K, V, W, Kb, Vt, Wb);
  attn_fwd  <<<dim3(S_LEN / 128, NH, 2), 256, 0, stream>>>(Q, Kb, Vt, Xws);
  proj_prelu<<<dim3(2 * S_LEN / 128, EMB / 128), 512, 0, stream>>>(Xws, Wb, Bb, Pa, Out);
}

// Round 7
// 187.810 us; speedup vs baseline: 1.2971x; 1.2971x over previous
//
#include <hip/hip_runtime.h>
#include <hip/hip_bf16.h>

typedef __attribute__((ext_vector_type(8))) short bf16x8;
typedef __attribute__((ext_vector_type(4))) float f32x4;

#define S_LEN 2048
#define EMB   1024
#define NH    16
#define HD    64

// XOR-swizzled LDS addressing: 64-col bf16 tiles, 8-elem (16 B) chunks.
// elem(row, chunk) = row*64 + ((chunk ^ (row&7))*8).
// Staging writes AND all fragment reads are bank-uniform (8 lanes per
// 4-bank group covering all 32 banks -> 8-cyc optimum per b128).
// Verified round 6: SQ_LDS_BANK_CONFLICT == 0.
__device__ inline int swz(int row, int chunk) {
  return row * 64 + ((chunk ^ (row & 7)) << 3);
}

// K-row permutation: storing K row s at position [s5,s2,s4,s3,s1,s0] makes
// the exp(S^T) C-layout registers exactly the mfma_16x16x32 A-fragment for
// natural-order V; PV then uses K=32 MFMA with b128 V reads, no fixup.
// Correctness verified round 6 (absmax unchanged at 4.88e-4).
__device__ inline int kperm(int s) {
  return (s & 0x23) | ((s & 0x04) << 2) | ((s & 0x18) >> 1);
}

// Convert 8 contiguous f32 -> 8 bf16 (RNE) packed in a uint4, optional scale.
__device__ inline uint4 cvt8(const float* __restrict__ src, float scale) {
  float4 f0 = ((const float4*)src)[0];
  float4 f1 = ((const float4*)src)[1];
  __hip_bfloat16 t[8];
  t[0] = __float2bfloat16(f0.x * scale);
  t[1] = __float2bfloat16(f0.y * scale);
  t[2] = __float2bfloat16(f0.z * scale);
  t[3] = __float2bfloat16(f0.w * scale);
  t[4] = __float2bfloat16(f1.x * scale);
  t[5] = __float2bfloat16(f1.y * scale);
  t[6] = __float2bfloat16(f1.z * scale);
  t[7] = __float2bfloat16(f1.w * scale);
  return *(uint4*)t;
}

// ---------------------------------------------------------------------------
// prep: z<2 -> K/V reformat for batch b=z; z==2 -> W f32->bf16 convert.
//   Kb[((b*NH+h)*S + s)*64 + d]  (head-major, rows = keys)
//   Vt[((b*NH+h)*64 + d)*S + s]  (transposed, rows = dims)
// ---------------------------------------------------------------------------
__global__ __launch_bounds__(256)
void prep(const float* __restrict__ K, const float* __restrict__ V,
          const float* __restrict__ W,
          __hip_bfloat16* __restrict__ Kb, __hip_bfloat16* __restrict__ Vt,
          __hip_bfloat16* __restrict__ Wb) {
  const int tid = threadIdx.x;
  if (blockIdx.z == 2) {   // W convert: 512 virtual blocks x 2048 elems
    const int widx = blockIdx.y * 32 + blockIdx.x;
    const int i = (widx * 256 + tid) * 8;
    *(uint4*)(Wb + i) = cvt8(W + i, 1.0f);
    return;
  }
  __shared__ float vt[64 * 65];
  const int st = blockIdx.x, h = blockIdx.y, b = blockIdx.z;
  const size_t srcbase = ((size_t)(b * S_LEN + st * 64)) * EMB + h * HD;
  const size_t kvb = ((size_t)(b * NH + h) * S_LEN + st * 64) * HD;
  const size_t vtb = ((size_t)(b * NH + h) * HD) * S_LEN + st * 64;

  for (int c = tid; c < 512; c += 256) {
    const int r = c >> 3, c8 = (c & 7) * 8;
    *(uint4*)(Kb + kvb + r * HD + c8) = cvt8(K + srcbase + (size_t)r * EMB + c8, 1.0f);
    const float* vsrc = V + srcbase + (size_t)r * EMB + c8;
    float4 a = ((const float4*)vsrc)[0];
    float4 d4 = ((const float4*)vsrc)[1];
    float tv[8] = {a.x, a.y, a.z, a.w, d4.x, d4.y, d4.z, d4.w};
    #pragma unroll
    for (int j = 0; j < 8; ++j) vt[r * 65 + c8 + j] = tv[j];
  }
  __syncthreads();
  for (int c = tid; c < 512; c += 256) {
    const int d = c >> 3, s8 = (c & 7) * 8;
    __hip_bfloat16 t[8];
    #pragma unroll
    for (int j = 0; j < 8; ++j)
      t[j] = __float2bfloat16(vt[(s8 + j) * 65 + d]);
    *(uint4*)(Vt + vtb + (size_t)d * S_LEN + s8) = *(uint4*)t;
  }
}

// ---------------------------------------------------------------------------
// Flash attention v7 = v4 skeleton (512 thr, 8 waves x 16 queries, 16
// waves/CU, double-buffered K/V + register prefetch, 1 barrier/iter, VGPR~60
// no spill) + v5/v6 LDS machinery (XOR swizzle -> 0 bank conflicts, kperm'd
// K rows -> K=32 PV MFMAs with b128 V reads straight from registers).
// S^T = K Q^T; exp(S^T) is directly the PV A-operand. No P LDS round-trip.
// ---------------------------------------------------------------------------
__global__ __launch_bounds__(512, 4)
void attn_fwd(const float* __restrict__ Q,
              const __hip_bfloat16* __restrict__ Kb,
              const __hip_bfloat16* __restrict__ Vt,
              __hip_bfloat16* __restrict__ O)
{
  __shared__ __align__(16) __hip_bfloat16 qs[128 * 64];     // 16 KB
  __shared__ __align__(16) __hip_bfloat16 ks[2][64 * 64];   // 16 KB [key][dim]
  __shared__ __align__(16) __hip_bfloat16 vs[2][64 * 64];   // 16 KB [dim][key]

  const int qt   = blockIdx.x;
  const int h    = blockIdx.y;
  const int b    = blockIdx.z;
  const int tid  = threadIdx.x;
  const int wave = tid >> 6;
  const int lane = tid & 63;
  const int ln   = lane & 15;
  const int qd   = lane >> 4;

  const size_t baseQ = ((size_t)(b * S_LEN + qt * 128)) * EMB + h * HD;
  const size_t kvb   = ((size_t)(b * NH + h) * S_LEN) * HD;
  const size_t vtb   = ((size_t)(b * NH + h) * HD) * S_LEN;

  // staging: 512 chunks per tile, 512 threads -> 1 chunk each
  const int r0 = tid >> 3, cc = tid & 7;
  const int kpos = swz(kperm(r0), cc);   // loop-invariant write addrs
  const int vpos = swz(r0, cc);

  // prefetch tile 0
  uint4 kreg = *(const uint4*)(Kb + kvb + (size_t)r0 * HD + cc * 8);
  uint4 vreg = *(const uint4*)(Vt + vtb + (size_t)r0 * S_LEN + cc * 8);

  // stage Q (f32 -> bf16, scale = 0.125*log2(e); P = exp2(S'))
  const float qscale = 0.125f * 1.44269504088896f;
  #pragma unroll
  for (int i = 0; i < 2; ++i) {
    const int c = tid + 512 * i, row = c >> 3, ch = c & 7;
    *(uint4*)&qs[swz(row, ch)] = cvt8(Q + baseQ + (size_t)row * EMB + ch * 8, qscale);
  }
  // write tile 0, prefetch tile 1
  *(uint4*)&ks[0][kpos] = kreg;
  *(uint4*)&vs[0][vpos] = vreg;
  kreg = *(const uint4*)(Kb + kvb + (size_t)(64 + r0) * HD + cc * 8);
  vreg = *(const uint4*)(Vt + vtb + (size_t)r0 * S_LEN + 64 + cc * 8);
  __syncthreads();   // qs + buf0 ready

  // Q B-fragments (n = query = ln, k = qd*8+j), loop-invariant
  bf16x8 aq[2];
  #pragma unroll
  for (int kh = 0; kh < 2; ++kh)
    aq[kh] = *(const bf16x8*)&qs[swz(wave * 16 + ln, kh * 4 + qd)];

  f32x4 oacc[4] = {};   // [dn]; C: col=dim=ln, row=query=qd*4+r
  float lsum = 0.f;

  for (int kt = 0; kt < S_LEN / 64; ++kt) {
    const int cur = kt & 1;
    if (kt + 1 < S_LEN / 64) {     // regs loaded one full iter ago: no stall
      *(uint4*)&ks[1 - cur][kpos] = kreg;
      *(uint4*)&vs[1 - cur][vpos] = vreg;
      if (kt + 2 < S_LEN / 64) {
        kreg = *(const uint4*)(Kb + kvb + (size_t)((kt + 2) * 64 + r0) * HD + cc * 8);
        vreg = *(const uint4*)(Vt + vtb + (size_t)r0 * S_LEN + (kt + 2) * 64 + cc * 8);
      }
    }

    // ---- S^T = K Q^T (rows = permuted keys) ----
    f32x4 sf[4];
    #pragma unroll
    for (int kt16 = 0; kt16 < 4; ++kt16) {
      bf16x8 ak0 = *(const bf16x8*)&ks[cur][swz(kt16 * 16 + ln, qd)];
      bf16x8 ak1 = *(const bf16x8*)&ks[cur][swz(kt16 * 16 + ln, 4 + qd)];
      f32x4 acc = {};
      acc = __builtin_amdgcn_mfma_f32_16x16x32_bf16(ak0, aq[0], acc, 0, 0, 0);
      acc = __builtin_amdgcn_mfma_f32_16x16x32_bf16(ak1, aq[1], acc, 0, 0, 0);
      sf[kt16] = acc;
    }

    // ---- P = exp2(S'); pack straight into K=32 A-fragments ----
    // key at k-index qd*8+j lives at S^T tile kt16 = t*2+(j>>2), reg j&3
    bf16x8 ap[2];
    #pragma unroll
    for (int t = 0; t < 2; ++t)
      #pragma unroll
      for (int j = 0; j < 8; ++j) {
        const float p = exp2f(sf[t * 2 + (j >> 2)][j & 3]);
        lsum += p;
        __hip_bfloat16 hb = __float2bfloat16(p);
        ap[t][j] = *(short*)&hb;
      }

    // ---- O += P V : K=32 MFMA, b128 V reads from vs[dim][key] ----
    #pragma unroll
    for (int t = 0; t < 2; ++t)
      #pragma unroll
      for (int dn = 0; dn < 4; ++dn) {
        bf16x8 bv = *(const bf16x8*)&vs[cur][swz(dn * 16 + ln, t * 4 + qd)];
        oacc[dn] = __builtin_amdgcn_mfma_f32_16x16x32_bf16(ap[t], bv, oacc[dn], 0, 0, 0);
      }

    __syncthreads();   // single barrier per iteration
  }

  // ---- epilogue: reduce lsum across quads, redistribute, normalize ----
  lsum += __shfl_xor(lsum, 16);
  lsum += __shfl_xor(lsum, 32);
  #pragma unroll
  for (int r = 0; r < 4; ++r) {
    const float inv = 1.f / __shfl(lsum, qd * 4 + r);
    const int row = wave * 16 + qd * 4 + r;
    #pragma unroll
    for (int dn = 0; dn < 4; ++dn)
      O[baseQ + (size_t)row * EMB + dn * 16 + ln] =
          __float2bfloat16(oacc[dn][r] * inv);
  }
}

// ---------------------------------------------------------------------------
// Projection: Out = PReLU(X @ W^T + b). 128x128 tile, 512 thr = 8 waves in a
// 4(M) x 2(N) grid (32 rows x 64 cols each). XOR-swizzled LDS (conflict-
// free), double-buffered, one barrier per k-iteration.
// ---------------------------------------------------------------------------
__global__ __launch_bounds__(512, 2)
void proj_prelu(const __hip_bfloat16* __restrict__ X,
                const __hip_bfloat16* __restrict__ Wb,
                const float* __restrict__ Bv,
                const float* __restrict__ Pa,
                float* __restrict__ Out)
{
  __shared__ __align__(16) __hip_bfloat16 xs[2][128 * 64];   // 32 KB
  __shared__ __align__(16) __hip_bfloat16 wsm[2][128 * 64];  // 32 KB

  const int m0   = blockIdx.x * 128;
  const int n0   = blockIdx.y * 128;
  const int tid  = threadIdx.x;
  const int wave = tid >> 6;
  const int wm   = wave >> 1;      // 0..3 : 32-row strip
  const int wn   = wave & 1;       // 0..1 : 64-col strip
  const int lane = tid & 63;
  const int ln   = lane & 15;
  const int qd   = lane >> 4;

  // staging: 1024 chunks per array / 512 thr = 2 each
  const int ra = tid >> 3, rb = ra + 64, cc = tid & 7;
  const int pa = swz(ra, cc), pb = swz(rb, cc);

  f32x4 acc[2][4] = {};   // [mf][nf]

  uint4 xrg[2], wrg[2];
  xrg[0] = *(const uint4*)(X  + (size_t)(m0 + ra) * EMB + cc * 8);
  xrg[1] = *(const uint4*)(X  + (size_t)(m0 + rb) * EMB + cc * 8);
  wrg[0] = *(const uint4*)(Wb + (size_t)(n0 + ra) * EMB + cc * 8);
  wrg[1] = *(const uint4*)(Wb + (size_t)(n0 + rb) * EMB + cc * 8);
  *(uint4*)&xs[0][pa]  = xrg[0];  *(uint4*)&xs[0][pb]  = xrg[1];
  *(uint4*)&wsm[0][pa] = wrg[0];  *(uint4*)&wsm[0][pb] = wrg[1];
  xrg[0] = *(const uint4*)(X  + (size_t)(m0 + ra) * EMB + 64 + cc * 8);
  xrg[1] = *(const uint4*)(X  + (size_t)(m0 + rb) * EMB + 64 + cc * 8);
  wrg[0] = *(const uint4*)(Wb + (size_t)(n0 + ra) * EMB + 64 + cc * 8);
  wrg[1] = *(const uint4*)(Wb + (size_t)(n0 + rb) * EMB + 64 + cc * 8);
  __syncthreads();

  for (int kt = 0; kt < EMB / 64; ++kt) {
    const int cur = kt & 1;
    if (kt + 1 < EMB / 64) {
      *(uint4*)&xs[1 - cur][pa]  = xrg[0];  *(uint4*)&xs[1 - cur][pb]  = xrg[1];
      *(uint4*)&wsm[1 - cur][pa] = wrg[0];  *(uint4*)&wsm[1 - cur][pb] = wrg[1];
      if (kt + 2 < EMB / 64) {
        const int ko = (kt + 2) * 64;
        xrg[0] = *(const uint4*)(X  + (size_t)(m0 + ra) * EMB + ko + cc * 8);
        xrg[1] = *(const uint4*)(X  + (size_t)(m0 + rb) * EMB + ko + cc * 8);
        wrg[0] = *(const uint4*)(Wb + (size_t)(n0 + ra) * EMB + ko + cc * 8);
        wrg[1] = *(const uint4*)(Wb + (size_t)(n0 + rb) * EMB + ko + cc * 8);
      }
    }

    #pragma unroll
    for (int kh = 0; kh < 2; ++kh) {
      bf16x8 ax[2], bw[4];
      #pragma unroll
      for (int mf = 0; mf < 2; ++mf)
        ax[mf] = *(const bf16x8*)&xs[cur][swz(wm * 32 + mf * 16 + ln, kh * 4 + qd)];
      #pragma unroll
      for (int nf = 0; nf < 4; ++nf)
        bw[nf] = *(const bf16x8*)&wsm[cur][swz(wn * 64 + nf * 16 + ln, kh * 4 + qd)];
      #pragma unroll
      for (int mf = 0; mf < 2; ++mf)
        #pragma unroll
        for (int nf = 0; nf < 4; ++nf)
          acc[mf][nf] = __builtin_amdgcn_mfma_f32_16x16x32_bf16(
              ax[mf], bw[nf], acc[mf][nf], 0, 0, 0);
    }
    __syncthreads();
  }

  const float a = Pa[0];
  #pragma unroll
  for (int nf = 0; nf < 4; ++nf) {
    const float bn = Bv[n0 + wn * 64 + nf * 16 + ln];
    #pragma unroll
    for (int mf = 0; mf < 2; ++mf)
      #pragma unroll
      for (int r = 0; r < 4; ++r) {
        float y = acc[mf][nf][r] + bn;
        y = (y >= 0.f) ? y : a * y;
        Out[(size_t)(m0 + wm * 32 + mf * 16 + qd * 4 + r) * EMB +
            n0 + wn * 64 + nf * 16 + ln] = y;
      }
  }
}

extern "C" void kernel_launch(void* const* d_in, const int* in_sizes, int n_in,
                              void* d_out, int out_size, void* d_ws, size_t ws_size,
                              hipStream_t stream) {
  const float* Q  = (const float*)d_in[0];
  const float* K  = (const float*)d_in[1];
  const float* V  = (const float*)d_in[2];
  const float* W  = (const float*)d_in[3];
  const float* Bb = (const float*)d_in[4];
  const float* Pa = (const float*)d_in[5];
  float* Out = (float*)d_out;

  // workspace (bytes): X 0..8M, Kb 8M..16M, Vt 16M..24M, Wb 24M..26M
  char* ws = (char*)d_ws;
  __hip_bfloat16* Xws = (__hip_bfloat16*)(ws);
  __hip_bfloat16* Kb  = (__hip_bfloat16*)(ws + (8u  << 20));
  __hip_bfloat16* Vt  = (__hip_bfloat16*)(ws + (16u << 20));
  __hip_bfloat16* Wb  = (__hip_bfloat16*)(ws + (24u << 20));

  prep      <<<dim3(S_LEN / 64, NH, 3), 256, 0, stream>>>(K, V, W, Kb, Vt, Wb);
  attn_fwd  <<<dim3(S_LEN / 128, NH, 2), 512, 0, stream>>>(Q, Kb, Vt, Xws);
  proj_prelu<<<dim3(2 * S_LEN / 128, EMB / 128), 512, 0, stream>>>(Xws, Wb, Bb, Pa, Out);
}